// Round 1
// baseline (155.850 us; speedup 1.0000x reference)
//
#include <hip/hip_runtime.h>
#include <cmath>

#define NEG_INF (-1.0e30f)

static constexpr int B = 256;
static constexpr int N = 65536;
static constexpr int THREADS = 1024;
static constexpr float C_OFF = 40.96f;  // = 64 * 0.8^2, upper bound of both logits

__device__ __forceinline__ float wave_sum_f(float v) {
#pragma unroll
  for (int off = 32; off >= 1; off >>= 1) v += __shfl_xor(v, off, 64);
  return v;
}
__device__ __forceinline__ int wave_sum_i(int v) {
#pragma unroll
  for (int off = 32; off >= 1; off >>= 1) v += __shfl_xor(v, off, 64);
  return v;
}

// Merge this lane's descending-sorted 16-list with XOR-partner lane's list,
// keeping the top-16 of the union (bitonic top-k merge).
__device__ __forceinline__ void merge_lists_shfl(float t[16], int off) {
  float b[16];
#pragma unroll
  for (int i = 0; i < 16; ++i) b[i] = __shfl_xor(t[i], off, 64);
  float c[16];
  // top-16 multiset of union(a,b); sequence is bitonic
#pragma unroll
  for (int i = 0; i < 16; ++i) c[i] = fmaxf(t[i], b[15 - i]);
  // bitonic merge -> descending sorted
#pragma unroll
  for (int s = 8; s >= 1; s >>= 1) {
#pragma unroll
    for (int i = 0; i < 16; ++i) {
      if ((i & s) == 0) {
        float lo = c[i], hi = c[i + s];
        c[i] = fmaxf(lo, hi);
        c[i + s] = fminf(lo, hi);
      }
    }
  }
#pragma unroll
  for (int i = 0; i < 16; ++i) t[i] = c[i];
}

__device__ __forceinline__ void process_elem(float s, float l, float& s_p,
                                             float& s_n, int& nn, float t[16]) {
  const bool pos = l > 0.5f;
  const bool neg = l < 0.25f;
  // logit_p = 64*relu(0.8-s)^2 ; logit_n = 64*relu(s-0.2)^2 (both >= 0)
  float dp = 0.8f - s;
  float lp = (dp > 0.f) ? 64.f * dp * dp : 0.f;
  float dn = s - 0.2f;
  float ln_ = (dn > 0.f) ? 64.f * dn * dn : 0.f;
  // masks are disjoint -> one exp per element
  float arg = pos ? (lp - C_OFF) : (neg ? (ln_ - C_OFF) : -1.0e30f);
  float e = __expf(arg);
  if (pos) s_p += e;
  if (neg) {
    s_n += e;
    ++nn;
    if (s > t[9]) {  // maintain sorted-descending top-10 (t[10..15] stay pad)
      t[9] = s;
#pragma unroll
      for (int i = 9; i > 0; --i) {
        float a = t[i - 1], bb = t[i];
        t[i - 1] = fmaxf(a, bb);
        t[i] = fminf(a, bb);
      }
    }
  }
}

__global__ void __launch_bounds__(THREADS) ranking_row_kernel(
    const float* __restrict__ sim, const float* __restrict__ label,
    float* __restrict__ row_loss) {
  const int row = blockIdx.x;
  const int tid = threadIdx.x;
  const float4* sim4 = reinterpret_cast<const float4*>(sim) + (size_t)row * (N / 4);
  const float4* lab4 = reinterpret_cast<const float4*>(label) + (size_t)row * (N / 4);

  float s_p = 0.f, s_n = 0.f;
  int nn = 0;
  float t[16];
#pragma unroll
  for (int i = 0; i < 16; ++i) t[i] = NEG_INF;

  constexpr int ITER = N / 4 / THREADS;  // 16
#pragma unroll 4
  for (int it = 0; it < ITER; ++it) {
    float4 sv = sim4[it * THREADS + tid];
    float4 lv = lab4[it * THREADS + tid];
    process_elem(sv.x, lv.x, s_p, s_n, nn, t);
    process_elem(sv.y, lv.y, s_p, s_n, nn, t);
    process_elem(sv.z, lv.z, s_p, s_n, nn, t);
    process_elem(sv.w, lv.w, s_p, s_n, nn, t);
  }

  // intra-wave reductions
  s_p = wave_sum_f(s_p);
  s_n = wave_sum_f(s_n);
  nn = wave_sum_i(nn);
#pragma unroll
  for (int off = 1; off < 64; off <<= 1) merge_lists_shfl(t, off);

  __shared__ float ls_p[16], ls_n[16];
  __shared__ int ls_c[16];
  __shared__ float ltop[16][16];
  const int wave = tid >> 6, lane = tid & 63;
  if (lane == 0) {
    ls_p[wave] = s_p;
    ls_n[wave] = s_n;
    ls_c[wave] = nn;
#pragma unroll
    for (int i = 0; i < 16; ++i) ltop[wave][i] = t[i];
  }
  __syncthreads();

  if (wave == 0) {
    // lanes 0..15 each hold one wave's top-16; butterfly-merge them
    float m[16];
    if (lane < 16) {
#pragma unroll
      for (int i = 0; i < 16; ++i) m[i] = ltop[lane][i];
    } else {
#pragma unroll
      for (int i = 0; i < 16; ++i) m[i] = NEG_INF;
    }
    merge_lists_shfl(m, 1);
    merge_lists_shfl(m, 2);
    merge_lists_shfl(m, 4);
    merge_lists_shfl(m, 8);

    float sp = (lane < 16) ? ls_p[lane] : 0.f;
    float sn = (lane < 16) ? ls_n[lane] : 0.f;
    int cn = (lane < 16) ? ls_c[lane] : 0;
    sp = wave_sum_f(sp);
    sn = wave_sum_f(sn);
    cn = wave_sum_i(cn);

    if (lane == 0) {
      // any positives <=> sp > 0 (each pos term >= exp(-40.96) > 0)
      float lse_p = (sp > 0.f) ? (C_OFF + __logf(sp)) : 0.f;
      float lse_n_all = (sn > 0.f) ? (C_OFF + __logf(sn)) : NEG_INF;

      // top-10 logsumexp (m[0..9] = top-10 negative sims, pad = -1e30 -> logit -0)
      float mx = NEG_INF;
      float lg[10];
#pragma unroll
      for (int i = 0; i < 10; ++i) {
        float v = m[i];
        float a = fmaxf(v - 0.2f, 0.f);
        float lo = a * (v - 0.2f) * 64.f;
        lg[i] = lo;
        mx = fmaxf(mx, lo);
      }
      float ss = 0.f;
#pragma unroll
      for (int i = 0; i < 10; ++i) ss += __expf(lg[i] - mx);
      float lse_n_top = mx + __logf(ss);

      float lse_n = (cn > 20) ? lse_n_top : lse_n_all;
      float x = lse_n + lse_p;
      // softplus(x) = max(x,0) + log1p(exp(-|x|))
      float loss = fmaxf(x, 0.f) + log1pf(__expf(-fabsf(x)));
      row_loss[row] = loss;
    }
  }
}

__global__ void __launch_bounds__(256) final_reduce_kernel(
    const float* __restrict__ row_loss, float* __restrict__ out) {
  const int tid = threadIdx.x;
  float v = row_loss[tid];
  v = wave_sum_f(v);
  __shared__ float ws[4];
  if ((tid & 63) == 0) ws[tid >> 6] = v;
  __syncthreads();
  if (tid == 0) out[0] = (ws[0] + ws[1] + ws[2] + ws[3]) * (1.0f / 256.0f);
}

extern "C" void kernel_launch(void* const* d_in, const int* in_sizes, int n_in,
                              void* d_out, int out_size, void* d_ws, size_t ws_size,
                              hipStream_t stream) {
  const float* sim = (const float*)d_in[0];
  const float* label = (const float*)d_in[1];
  float* out = (float*)d_out;
  float* rows = (float*)d_ws;  // 256 floats of scratch
  ranking_row_kernel<<<dim3(B), dim3(THREADS), 0, stream>>>(sim, label, rows);
  final_reduce_kernel<<<dim3(1), dim3(256), 0, stream>>>(rows, out);
}